// Round 14
// baseline (440.083 us; speedup 1.0000x reference)
//
#include <hip/hip_runtime.h>
#include <hip/hip_bf16.h>
#include <cstdint>

constexpr int HIDDEN = 128, CTXD = 2048, HEADS = 4, NLAYERS = 3;
constexpr int KRBF = 720, KPAD = 736;  // 736 = 23 * 32
constexpr int KXH = 256;               // concat [x | h] K-dim

typedef __bf16 bf16x8 __attribute__((ext_vector_type(8)));
typedef float f32x4 __attribute__((ext_vector_type(4)));

static __device__ __forceinline__ unsigned short f2bf(float f) {
    union { float f; unsigned u; } v; v.f = f;
    unsigned r = v.u + 0x7fffu + ((v.u >> 16) & 1u);
    return (unsigned short)(r >> 16);
}
static __device__ __forceinline__ float bf2f(unsigned short s) {
    union { unsigned u; float f; } v; v.u = ((unsigned)s) << 16; return v.f;
}

// ================= merged input-only prep (flat-grid partitioned) =================
__global__ __launch_bounds__(256) void k_misc(const float* __restrict__ W1,
                                              unsigned short* __restrict__ W1t,
                                              const float* __restrict__ W2,
                                              unsigned short* __restrict__ W2bf,
                                              const float* __restrict__ ctx,
                                              const float* __restrict__ b2,
                                              unsigned short* __restrict__ cpre,
                                              int* __restrict__ cnt,
                                              const int* __restrict__ at,
                                              const float* __restrict__ embW,
                                              const float* __restrict__ embB,
                                              float* __restrict__ x,
                                              unsigned short* __restrict__ xh,
                                              const float* __restrict__ gatW,
                                              unsigned short* __restrict__ gatWt,
                                              int N, int NG,
                                              int e0, int e1, int e2, int e3, int e4) {
    __shared__ unsigned short t[32][34];
    int b = blockIdx.x, tid = threadIdx.x;
    if (b < e0) {  // W1t
        int i = b * 256 + tid;
        if (i < 128 * KPAD) {
            int c = i / KPAD, k = i % KPAD;
            W1t[i] = (k < KRBF) ? f2bf(W1[(size_t)k * 128 + c]) : (unsigned short)0;
        }
    } else if (b < e1) {  // W2bf
        int i = (b - e0) * 256 + tid;
        if (i < 128 * CTXD) W2bf[i] = f2bf(W2[i]);
    } else if (b < e2) {  // cpre
        int i = (b - e1) * 256 + tid;
        if (i < NG * CTXD) cpre[i] = f2bf(ctx[i] + b2[i % CTXD]);
    } else if (b < e3) {  // cnt init (self-loop)
        int i = (b - e2) * 256 + tid;
        if (i < N) cnt[i] = 1;
    } else if (b < e4) {  // embed
        int i = (b - e3) * 256 + tid;
        if (i < N * HIDDEN) {
            int n = i >> 7, c = i & 127;
            float v = embW[(size_t)at[n] * HIDDEN + c] + embB[c];
            x[i] = v;
            xh[(size_t)n * KXH + c] = f2bf(v);
        }
    } else {  // gatW transpose: f32 [3][2176][512] -> bf16 [3][512][2176]
        int idx = b - e4;
        int bz = idx / (16 * 68);
        int rem = idx % (16 * 68);
        int bx = rem % 16, by = rem / 16;
        int tx = tid & 31, ty = tid >> 5;
        const int R = 2176, C = 512;
        int c0 = bx * 32, r0 = by * 32;
        const float* s = gatW + (size_t)bz * R * C;
        unsigned short* d = gatWt + (size_t)bz * R * C;
        for (int rr = ty; rr < 32; rr += 8) {
            int r = r0 + rr, c = c0 + tx;
            t[rr][tx] = f2bf(s[(size_t)r * C + c]);
        }
        __syncthreads();
        for (int rr = ty; rr < 32; rr += 8) {
            int c = c0 + rr, r = r0 + tx;
            d[(size_t)c * R + r] = t[tx][rr];
        }
    }
}

// ------- shared MFMA GEMM core (prep GEMMs), double-buffered (1 barrier/K-step) -------
// MODE 0: bf16 out. MODE 2: f32 out.
template <int MODE>
__device__ __forceinline__ void gemm_core(unsigned short (*As)[128 * 40],
                                          unsigned short (*Bs)[128 * 40],
                                          const unsigned short* __restrict__ A, int lda, int M,
                                          const unsigned short* __restrict__ Bt, int ldb, int K,
                                          void* __restrict__ Cout, int ldc,
                                          int m0, int n0) {
    constexpr int LDT = 40;
    const int tid = threadIdx.x;
    const int lane = tid & 63, wid = tid >> 6;
    const int wr = (wid >> 1) * 64, wc = (wid & 1) * 64;
    const int sr = tid >> 1, sk = (tid & 1) * 16;
    f32x4 acc[4][4];
#pragma unroll
    for (int i = 0; i < 4; i++)
#pragma unroll
        for (int j = 0; j < 4; j++)
#pragma unroll
            for (int r = 0; r < 4; r++) acc[i][j][r] = 0.f;
    const int nst = K / 32;
    const int arow = min(m0 + sr, M - 1);
    const unsigned short* ap = A + (size_t)arow * lda + sk;
    const unsigned short* bp = Bt + (size_t)(n0 + sr) * ldb + sk;
    uint4 av0 = *(const uint4*)ap, av1 = *(const uint4*)(ap + 8);
    uint4 bv0 = *(const uint4*)bp, bv1 = *(const uint4*)(bp + 8);
    const int fr = lane & 15, kg = lane >> 4;
    for (int ks = 0; ks < nst; ++ks) {
        unsigned short* as = As[ks & 1];
        unsigned short* bs = Bs[ks & 1];
        *(uint4*)&as[sr * LDT + sk] = av0;
        *(uint4*)&as[sr * LDT + sk + 8] = av1;
        *(uint4*)&bs[sr * LDT + sk] = bv0;
        *(uint4*)&bs[sr * LDT + sk + 8] = bv1;
        __syncthreads();
        if (ks + 1 < nst) {  // prefetch next K-step; overlaps with MFMA below
            av0 = *(const uint4*)(ap + (ks + 1) * 32);
            av1 = *(const uint4*)(ap + (ks + 1) * 32 + 8);
            bv0 = *(const uint4*)(bp + (ks + 1) * 32);
            bv1 = *(const uint4*)(bp + (ks + 1) * 32 + 8);
        }
        bf16x8 afr[4], bfr[4];
#pragma unroll
        for (int i = 0; i < 4; i++) {
            afr[i] = *reinterpret_cast<const bf16x8*>(&as[(wr + i * 16 + fr) * LDT + kg * 8]);
            bfr[i] = *reinterpret_cast<const bf16x8*>(&bs[(wc + i * 16 + fr) * LDT + kg * 8]);
        }
#pragma unroll
        for (int i = 0; i < 4; i++)
#pragma unroll
            for (int j = 0; j < 4; j++)
                acc[i][j] = __builtin_amdgcn_mfma_f32_16x16x32_bf16(afr[i], bfr[j], acc[i][j], 0, 0, 0);
    }
    const int rg = lane >> 4;  // C/D: col = lane&15, row = (lane>>4)*4 + reg
#pragma unroll
    for (int i = 0; i < 4; i++) {
#pragma unroll
        for (int j = 0; j < 4; j++) {
            int col = n0 + wc + j * 16 + fr;
#pragma unroll
            for (int r = 0; r < 4; r++) {
                int row = m0 + wr + i * 16 + rg * 4 + r;
                if (row < M) {
                    float vv = acc[i][j][r];
                    if (MODE == 2) {
                        ((float*)Cout)[(size_t)row * ldc + col] = vv;
                    } else {
                        ((unsigned short*)Cout)[(size_t)row * ldc + col] = f2bf(vv);
                    }
                }
            }
        }
    }
}

// ============ merged: RBF-MFMA (blocks [0,nbRbf)) + prep GEMMs + Bc copy ============
__global__ __launch_bounds__(256) void k_rbfprep(const float* __restrict__ pos,
                                                 const unsigned short* __restrict__ W1t,
                                                 const float* __restrict__ b1,
                                                 const float* __restrict__ g,
                                                 const float* __restrict__ bb,
                                                 const float* __restrict__ bm,
                                                 const float* __restrict__ bv,
                                                 unsigned short* __restrict__ xh,
                                                 const unsigned short* __restrict__ gatWt,
                                                 const unsigned short* __restrict__ W2bf,
                                                 const unsigned short* __restrict__ cpre,
                                                 unsigned short* __restrict__ Bc,
                                                 float* __restrict__ cW,
                                                 int N, int NG, int nbRbf) {
    constexpr int LDT = 40;
    __shared__ unsigned short As[2][128 * LDT];
    __shared__ unsigned short Bs[2][128 * LDT];
    __shared__ float ps[128 * 3];
    const int bid = blockIdx.x;
    const int tid = threadIdx.x;
    if (bid >= nbRbf) {
        int idx = bid - nbRbf;
        if (idx < 12) {  // Bc[l][:,128:256] = Wc[l]^T @ W2^T
            int z = idx >> 2, mt = idx & 3;
            gemm_core<0>(As, Bs, gatWt + (size_t)z * 512 * 2176 + 128, 2176, 512,
                         W2bf, CTXD, CTXD, Bc + (size_t)z * 512 * KXH + 128, KXH,
                         mt * 128, 0);
        } else if (idx < 24) {  // cW[l] = cpre @ Wc[l]
            int z = (idx - 12) >> 2, nt = (idx - 12) & 3;
            gemm_core<2>(As, Bs, cpre, CTXD, NG, gatWt + (size_t)z * 512 * 2176 + 128, 2176,
                         CTXD, cW + (size_t)z * NG * 512, 512, 0, nt * 128);
        } else {  // Bc[l][o][0:128] = gatWt[l][o][0:128]
            int i = (idx - 24) * 256 + tid;
            if (i < NLAYERS * 512 * 128) {
                int lo = i >> 7, k = i & 127;
                Bc[(size_t)lo * KXH + k] = gatWt[(size_t)lo * 2176 + k];
            }
        }
        return;
    }
    // ---- RBF + Linear(720->128) via MFMA + BN + ReLU -> xh[:,128:256] ----
    const int lane = tid & 63, wid = tid >> 6;
    const int nb = bid * 128;
    for (int i = tid; i < 384; i += 256) {
        int n = nb + i / 3;
        ps[i] = (n < N) ? pos[(size_t)n * 3 + (i % 3)] : 1.0e9f;  // pad rows -> rbf = 0
    }
    __syncthreads();
    const int sr = tid >> 1, sk = (tid & 1) * 16;
    const int wr = (wid >> 1) * 64, wc = (wid & 1) * 64;
    const int fr = lane & 15, kg = lane >> 4;
    f32x4 acc[4][4];
#pragma unroll
    for (int i = 0; i < 4; i++)
#pragma unroll
        for (int j = 0; j < 4; j++)
#pragma unroll
            for (int r = 0; r < 4; r++) acc[i][j][r] = 0.f;
    const float p0 = ps[sr * 3], p1 = ps[sr * 3 + 1], p2 = ps[sr * 3 + 2];
    const unsigned short* bp = W1t + (size_t)sr * KPAD + sk;
    uint4 bv0 = *(const uint4*)bp, bv1 = *(const uint4*)(bp + 8);
    constexpr int NST = KPAD / 32;
    for (int ks = 0; ks < NST; ++ks) {
        unsigned short av[16];
#pragma unroll
        for (int j = 0; j < 16; j++) {
            int kglob = ks * 32 + sk + j;
            float v = 0.f;
            if (kglob < KRBF) {
                int d = kglob / 240, bin = kglob % 240;
                float mu = -30.f + (60.f / 239.f) * (float)bin;
                float p = (d == 0) ? p0 : ((d == 1) ? p1 : p2);
                float df = p - mu;
                v = __expf(-0.5f * df * df);
            }
            av[j] = f2bf(v);
        }
        __syncthreads();
        *(uint4*)&As[0][sr * LDT + sk] = *(const uint4*)&av[0];
        *(uint4*)&As[0][sr * LDT + sk + 8] = *(const uint4*)&av[8];
        *(uint4*)&Bs[0][sr * LDT + sk] = bv0;
        *(uint4*)&Bs[0][sr * LDT + sk + 8] = bv1;
        __syncthreads();
        if (ks + 1 < NST) {
            const unsigned short* bp2 = W1t + (size_t)sr * KPAD + (ks + 1) * 32 + sk;
            bv0 = *(const uint4*)bp2;
            bv1 = *(const uint4*)(bp2 + 8);
        }
        bf16x8 afr[4], bfr[4];
#pragma unroll
        for (int i = 0; i < 4; i++) {
            afr[i] = *reinterpret_cast<const bf16x8*>(&As[0][(wr + i * 16 + fr) * LDT + kg * 8]);
            bfr[i] = *reinterpret_cast<const bf16x8*>(&Bs[0][(wc + i * 16 + fr) * LDT + kg * 8]);
        }
#pragma unroll
        for (int i = 0; i < 4; i++)
#pragma unroll
            for (int j = 0; j < 4; j++)
                acc[i][j] = __builtin_amdgcn_mfma_f32_16x16x32_bf16(afr[i], bfr[j], acc[i][j], 0, 0, 0);
    }
    const int rg = lane >> 4;
#pragma unroll
    for (int i = 0; i < 4; i++) {
#pragma unroll
        for (int j = 0; j < 4; j++) {
            int col = wc + j * 16 + fr;
            float sc = g[col] * rsqrtf(bv[col] + 1e-5f);
            float sh = bb[col] - bm[col] * sc;
            float bc = b1[col];
#pragma unroll
            for (int r = 0; r < 4; r++) {
                int row = nb + wr + i * 16 + rg * 4 + r;
                if (row < N) {
                    float y = (acc[i][j][r] + bc) * sc + sh;
                    y = fmaxf(y, 0.f);
                    xh[(size_t)row * KXH + 128 + col] = f2bf(y);
                }
            }
        }
    }
}

// ========= GAT per-layer node GEMM: dbuf LDS + bijective XCD-swizzled tiles =========
// 1D grid (4 * nTilesM). Swizzle gives each XCD a contiguous tile chunk so the 4
// col-tiles sharing an A row-tile run on ONE XCD -> A is L2-resident (fetched once).
__global__ __launch_bounds__(256) void k_gemm3(const unsigned short* __restrict__ A, int M,
                                               const unsigned short* __restrict__ Bt,
                                               unsigned short* __restrict__ C,
                                               const int* __restrict__ batch,
                                               const float* __restrict__ cw,
                                               const float* __restrict__ att_s,
                                               const float* __restrict__ att_d,
                                               float* __restrict__ a_src,
                                               float* __restrict__ a_dst) {
    constexpr int LDT = 40;
    __shared__ unsigned short As[2][128 * LDT];
    __shared__ unsigned short Bs[2][128 * LDT];
    const int tid = threadIdx.x;
    const int lane = tid & 63, wid = tid >> 6;
    // bijective XCD swizzle (8 XCDs, round-robin hw assignment assumed)
    const int nwg = gridDim.x;
    const int q = nwg >> 3, r = nwg & 7;
    const int orig = blockIdx.x;
    const int xcd = orig & 7, slot = orig >> 3;
    const int tile = (xcd < r) ? (xcd * (q + 1) + slot) : (r * (q + 1) + (xcd - r) * q + slot);
    const int n0 = (tile & 3) * 128, m0 = (tile >> 2) * 128;
    const int wr = (wid >> 1) * 64, wc = (wid & 1) * 64;
    const int sr = tid >> 1, sk = (tid & 1) * 16;
    f32x4 acc[4][4];
#pragma unroll
    for (int i = 0; i < 4; i++)
#pragma unroll
        for (int j = 0; j < 4; j++)
#pragma unroll
            for (int r2 = 0; r2 < 4; r2++) acc[i][j][r2] = 0.f;
    const int arow = min(m0 + sr, M - 1);
    const unsigned short* ap = A + (size_t)arow * KXH + sk;
    const unsigned short* bp = Bt + (size_t)(n0 + sr) * KXH + sk;
    uint4 av0 = *(const uint4*)ap, av1 = *(const uint4*)(ap + 8);
    uint4 bv0 = *(const uint4*)bp, bv1 = *(const uint4*)(bp + 8);
    const int fr = lane & 15, kg = lane >> 4;
    constexpr int NST = KXH / 32;  // 8
    for (int ks = 0; ks < NST; ++ks) {
        unsigned short* as = As[ks & 1];
        unsigned short* bs = Bs[ks & 1];
        *(uint4*)&as[sr * LDT + sk] = av0;
        *(uint4*)&as[sr * LDT + sk + 8] = av1;
        *(uint4*)&bs[sr * LDT + sk] = bv0;
        *(uint4*)&bs[sr * LDT + sk + 8] = bv1;
        __syncthreads();
        if (ks + 1 < NST) {  // prefetch next K-step; overlaps with MFMA below
            av0 = *(const uint4*)(ap + (ks + 1) * 32);
            av1 = *(const uint4*)(ap + (ks + 1) * 32 + 8);
            bv0 = *(const uint4*)(bp + (ks + 1) * 32);
            bv1 = *(const uint4*)(bp + (ks + 1) * 32 + 8);
        }
        bf16x8 afr[4], bfr[4];
#pragma unroll
        for (int i = 0; i < 4; i++) {
            afr[i] = *reinterpret_cast<const bf16x8*>(&as[(wr + i * 16 + fr) * LDT + kg * 8]);
            bfr[i] = *reinterpret_cast<const bf16x8*>(&bs[(wc + i * 16 + fr) * LDT + kg * 8]);
        }
#pragma unroll
        for (int i = 0; i < 4; i++)
#pragma unroll
            for (int j = 0; j < 4; j++)
                acc[i][j] = __builtin_amdgcn_mfma_f32_16x16x32_bf16(afr[i], bfr[j], acc[i][j], 0, 0, 0);
    }
    const int rg = lane >> 4;  // C/D: col = lane&15, row = (lane>>4)*4 + reg
    float pssum[4][4], pdsum[4][4];
#pragma unroll
    for (int i = 0; i < 4; i++)
#pragma unroll
        for (int r2 = 0; r2 < 4; r2++) { pssum[i][r2] = 0.f; pdsum[i][r2] = 0.f; }
#pragma unroll
    for (int i = 0; i < 4; i++) {
#pragma unroll
        for (int j = 0; j < 4; j++) {
            int col = n0 + wc + j * 16 + fr;
            float asw = att_s[col], adw = att_d[col];
#pragma unroll
            for (int r2 = 0; r2 < 4; r2++) {
                int row = m0 + wr + i * 16 + rg * 4 + r2;
                if (row < M) {
                    float vv = acc[i][j][r2] + cw[(size_t)batch[row] * 512 + col];
                    C[(size_t)row * 512 + col] = f2bf(vv);
                    pssum[i][r2] += vv * asw;
                    pdsum[i][r2] += vv * adw;
                }
            }
        }
    }
    __syncthreads();  // LDS is dead; reuse for cross-wave att combine
    float* lat = (float*)&As[0][0];  // [4 waves][64 rows][2]
#pragma unroll
    for (int i = 0; i < 4; i++) {
#pragma unroll
        for (int r2 = 0; r2 < 4; r2++) {
            float s = pssum[i][r2], d = pdsum[i][r2];
#pragma unroll
            for (int dd = 1; dd < 16; dd <<= 1) {
                s += __shfl_xor(s, dd);
                d += __shfl_xor(d, dd);
            }
            if (fr == 0) {
                int k = i * 16 + rg * 4 + r2;
                lat[(wid * 64 + k) * 2] = s;
                lat[(wid * 64 + k) * 2 + 1] = d;
            }
        }
    }
    __syncthreads();
    if ((wid & 1) == 0) {
        int k = lane;
        int row = m0 + (wid >> 1) * 64 + k;
        if (row < M) {
            float s = lat[(wid * 64 + k) * 2] + lat[((wid + 1) * 64 + k) * 2];
            float d = lat[(wid * 64 + k) * 2 + 1] + lat[((wid + 1) * 64 + k) * 2 + 1];
            int head = n0 >> 7;
            a_src[(size_t)row * 4 + head] = s;
            a_dst[(size_t)row * 4 + head] = d;
        }
    }
}

// ---------------- CSR build ----------------
__global__ void k_cnt(const int* __restrict__ ei, int E, int* cnt) {
    int i = blockIdx.x * 256 + threadIdx.x;
    if (i < E) atomicAdd(&cnt[ei[E + i]], 1);
}
// one-pass exclusive scan: thread-serial chunks + single 1024-wide scan (2 barriers)
__global__ __launch_bounds__(1024) void k_scan(const int* __restrict__ cnt, int* __restrict__ rowptr,
                                               int* __restrict__ cursor, int n) {
    __shared__ int wsum[16];
    int tid = threadIdx.x, lane = tid & 63, wid = tid >> 6;
    int ch = (n + 1023) >> 10;
    int b = tid * ch, e = min(b + ch, n);
    if (b > n) b = n;
    int sum = 0;
    for (int i = b; i < e; i++) sum += cnt[i];
    int s = sum;
#pragma unroll
    for (int d = 1; d < 64; d <<= 1) {
        int t = __shfl_up(s, (unsigned)d);
        if (lane >= d) s += t;
    }
    if (lane == 63) wsum[wid] = s;
    __syncthreads();
    if (wid == 0 && lane < 16) {
        int ws = wsum[lane]; int t = ws;
#pragma unroll
        for (int d = 1; d < 16; d <<= 1) {
            int u = __shfl_up(t, (unsigned)d);
            if (lane >= d) t += u;
        }
        wsum[lane] = t - ws;  // exclusive wave offsets
    }
    __syncthreads();
    int run = wsum[wid] + (s - sum);  // exclusive prefix for this thread's chunk
    for (int i = b; i < e; i++) {
        rowptr[i] = run;
        cursor[i] = run;
        run += cnt[i];
    }
    if (e == n) rowptr[n] = run;  // thread(s) at the tail write the total (same value)
}
__global__ void k_fill(const int* __restrict__ ei, int E, int N, int* cursor, int* csrc) {
    int i = blockIdx.x * 256 + threadIdx.x;
    if (i >= E + N) return;
    int s, d;
    if (i < E) { s = ei[i]; d = ei[E + i]; }
    else { s = i - E; d = s; }
    int slot = atomicAdd(&cursor[d], 1);
    csrc[slot] = s;
}

// ---------------- GAT aggregation: one-pass softmax + LDS-staged 2-deep gather ----------------
__global__ __launch_bounds__(256) void k_agg(const int* __restrict__ rowptr,
                                             const int* __restrict__ csrc,
                                             const float* __restrict__ asrc,
                                             const float* __restrict__ adstv,
                                             const unsigned short* __restrict__ xs,
                                             const float* __restrict__ gbias,
                                             const float* __restrict__ bg,
                                             const float* __restrict__ bb,
                                             const float* __restrict__ bm,
                                             const float* __restrict__ bv,
                                             float* __restrict__ x,
                                             unsigned short* __restrict__ xh, int N) {
    __shared__ float wsh[4][64][4];
    __shared__ int ssh[4][64];
    int tid = threadIdx.x, lane = tid & 63, wid = tid >> 6;
    int n = blockIdx.x * 4 + wid;
    if (n >= N) return;
    int beg = rowptr[n], end = rowptr[n + 1];
    float4 ad = *(const float4*)(adstv + (size_t)n * 4);
    int nch = (end - beg + 63) >> 6;
    // phase A: online per-head max & denom (lane i owns edge beg+i of each chunk)
    float m0 = -1e30f, m1 = -1e30f, m2 = -1e30f, m3 = -1e30f;
    float s0 = 0.f, s1 = 0.f, s2 = 0.f, s3 = 0.f;
    float a0 = -1e30f, a1 = -1e30f, a2 = -1e30f, a3 = -1e30f;  // persisted (single-chunk reuse)
    int sv = 0;
    for (int base = beg; base < end; base += 64) {
        int idx = base + lane;
        float b0 = -1e30f, b1 = -1e30f, b2 = -1e30f, b3 = -1e30f;
        int s = 0;
        if (idx < end) {
            s = csrc[idx];
            float4 t = *(const float4*)(asrc + (size_t)s * 4);
            b0 = t.x + ad.x; b0 = b0 > 0.f ? b0 : 0.2f * b0;
            b1 = t.y + ad.y; b1 = b1 > 0.f ? b1 : 0.2f * b1;
            b2 = t.z + ad.z; b2 = b2 > 0.f ? b2 : 0.2f * b2;
            b3 = t.w + ad.w; b3 = b3 > 0.f ? b3 : 0.2f * b3;
        }
        float c0 = b0, c1 = b1, c2 = b2, c3 = b3;
#pragma unroll
        for (int d = 1; d < 64; d <<= 1) {
            c0 = fmaxf(c0, __shfl_xor(c0, d));
            c1 = fmaxf(c1, __shfl_xor(c1, d));
            c2 = fmaxf(c2, __shfl_xor(c2, d));
            c3 = fmaxf(c3, __shfl_xor(c3, d));
        }
        float nm0 = fmaxf(m0, c0), nm1 = fmaxf(m1, c1), nm2 = fmaxf(m2, c2), nm3 = fmaxf(m3, c3);
        float e0 = (idx < end) ? __expf(b0 - nm0) : 0.f;
        float e1 = (idx < end) ? __expf(b1 - nm1) : 0.f;
        float e2 = (idx < end) ? __expf(b2 - nm2) : 0.f;
        float e3 = (idx < end) ? __expf(b3 - nm3) : 0.f;
#pragma unroll
        for (int d = 1; d < 64; d <<= 1) {
            e0 += __shfl_xor(e0, d); e1 += __shfl_xor(e1, d);
            e2 += __shfl_xor(e2, d); e3 += __shfl_xor(e3, d);
        }
        s0 = s0 * __expf(m0 - nm0) + e0; m0 = nm0;
        s1 = s1 * __expf(m1 - nm1) + e1; m1 = nm1;
        s2 = s2 * __expf(m2 - nm2) + e2; m2 = nm2;
        s3 = s3 * __expf(m3 - nm3) + e3; m3 = nm3;
        a0 = b0; a1 = b1; a2 = b2; a3 = b3; sv = s;
    }
    float i0 = 1.f / fmaxf(s0, 1e-16f), i1 = 1.f / fmaxf(s1, 1e-16f);
    float i2 = 1.f / fmaxf(s2, 1e-16f), i3 = 1.f / fmaxf(s3, 1e-16f);
    // phase B: weighted gather, per-edge weights staged in LDS (wave-private), 2-deep
    const int h = lane >> 4, c0i = (lane & 15) * 8;
    float acc[8];
#pragma unroll
    for (int j = 0; j < 8; j++) acc[j] = 0.f;
    for (int base = beg; base < end; base += 64) {
        int s; float w0, w1, w2, w3;
        if (nch == 1) {
            s = sv;
            w0 = __expf(a0 - m0) * i0; w1 = __expf(a1 - m1) * i1;
            w2 = __expf(a2 - m2) * i2; w3 = __expf(a3 - m3) * i3;
        } else {
            int idx = base + lane;
            float b0 = -1e30f, b1 = -1e30f, b2 = -1e30f, b3 = -1e30f;
            s = 0;
            if (idx < end) {
                s = csrc[idx];
                float4 t = *(const float4*)(asrc + (size_t)s * 4);
                b0 = t.x + ad.x; b0 = b0 > 0.f ? b0 : 0.2f * b0;
                b1 = t.y + ad.y; b1 = b1 > 0.f ? b1 : 0.2f * b1;
                b2 = t.z + ad.z; b2 = b2 > 0.f ? b2 : 0.2f * b2;
                b3 = t.w + ad.w; b3 = b3 > 0.f ? b3 : 0.2f * b3;
            }
            w0 = __expf(b0 - m0) * i0; w1 = __expf(b1 - m1) * i1;
            w2 = __expf(b2 - m2) * i2; w3 = __expf(b3 - m3) * i3;
        }
        ssh[wid][lane] = s;
        wsh[wid][lane][0] = w0; wsh[wid][lane][1] = w1;
        wsh[wid][lane][2] = w2; wsh[wid][lane][3] = w3;
        int cnt = min(64, end - base);
        int i = 0;
        for (; i + 2 <= cnt; i += 2) {
            int sa = ssh[wid][i], sb = ssh[wid][i + 1];
            float wa = wsh[wid][i][h], wb = wsh[wid][i + 1][h];
            uint4 ra = *(const uint4*)(xs + ((size_t)sa << 9) + (h << 7) + c0i);
            uint4 rb = *(const uint4*)(xs + ((size_t)sb << 9) + (h << 7) + c0i);
            const unsigned short* qa = (const unsigned short*)&ra;
            const unsigned short* qb = (const unsigned short*)&rb;
#pragma unroll
            for (int j = 0; j < 8; j++) acc[j] += wa * bf2f(qa[j]);
#pragma unroll
            for (int j = 0; j < 8; j++) acc[j] += wb * bf2f(qb[j]);
        }
        if (i < cnt) {
            int sa = ssh[wid][i];
            float wa = wsh[wid][i][h];
            uint4 ra = *(const uint4*)(xs + ((size_t)sa << 9) + (h << 7) + c0i);
            const unsigned short* qa = (const unsigned short*)&ra;
#pragma unroll
            for (int j = 0; j < 8; j++) acc[j] += wa * bf2f(qa[j]);
        }
    }
    // head mean across lanes (h = lane>>4)
#pragma unroll
    for (int j = 0; j < 8; j++) {
        acc[j] += __shfl_xor(acc[j], 16);
        acc[j] += __shfl_xor(acc[j], 32);
    }
    if (lane < 16) {
#pragma unroll
        for (int j = 0; j < 8; j++) {
            int c = c0i + j;
            float t = acc[j] * 0.25f + gbias[c];
            float sc = bg[c] * rsqrtf(bv[c] + 1e-5f);
            float y = (t - bm[c]) * sc + bb[c];
            float ge = 0.5f * y * (1.f + erff(y * 0.70710678118f));
            float xn = x[(size_t)n * 128 + c] + ge;
            x[(size_t)n * 128 + c] = xn;
            xh[(size_t)n * KXH + c] = f2bf(xn);
        }
    }
}

// ---------------- fused pool + final linear ----------------
__global__ __launch_bounds__(256) void k_pool(const float* __restrict__ x,
                                              const int* __restrict__ batch,
                                              const float* __restrict__ W,
                                              const float* __restrict__ bo,
                                              float* __restrict__ out, int N) {
    __shared__ float xg[128];
    __shared__ float tmp[256];
    __shared__ int bounds[2];
    int g = blockIdx.x, tid = threadIdx.x;
    if (tid < 2) {
        int key = g + tid, lo = 0, hi = N;
        while (lo < hi) { int mid = (lo + hi) >> 1; if (batch[mid] < key) lo = mid + 1; else hi = mid; }
        bounds[tid] = lo;
    }
    __syncthreads();
    int s = bounds[0], e = bounds[1];
    int c = tid & 127, rgp = tid >> 7;
    float a = 0.f;
    for (int n = s + rgp; n < e; n += 2) a += x[(size_t)n * 128 + c];
    tmp[tid] = a;
    __syncthreads();
    if (tid < 128) xg[tid] = tmp[tid] + tmp[tid + 128];
    __syncthreads();
    float cntf = (float)(e - s);
    for (int j = tid; j < 1024; j += 256) {
        float o = cntf * bo[j];
        for (int cc = 0; cc < 128; cc++) o += xg[cc] * W[(size_t)cc * 1024 + j];
        out[(size_t)g * 1024 + j] = o;
    }
}

extern "C" void kernel_launch(void* const* d_in, const int* in_sizes, int n_in,
                              void* d_out, int out_size, void* d_ws, size_t ws_size,
                              hipStream_t stream) {
    const int N = in_sizes[0];
    const int E = in_sizes[2] / 2;
    const int NG = in_sizes[5] / CTXD;
    const int* at = (const int*)d_in[0];
    const float* pos = (const float*)d_in[1];
    const int* ei = (const int*)d_in[2];
    const int* batch = (const int*)d_in[4];
    const float* ctx = (const float*)d_in[5];
    const float* embW = (const float*)d_in[6];
    const float* embB = (const float*)d_in[7];
    const float* W1 = (const float*)d_in[8];
    const float* b1 = (const float*)d_in[9];
    const float* rg = (const float*)d_in[10];
    const float* rb = (const float*)d_in[11];
    const float* rm = (const float*)d_in[12];
    const float* rv = (const float*)d_in[13];
    const float* W2 = (const float*)d_in[14];
    const float* b2 = (const float*)d_in[15];
    const float* gatW = (const float*)d_in[16];
    const float* atts = (const float*)d_in[17];
    const float* attd = (const float*)d_in[18];
    const float* gbias = (const float*)d_in[19];
    const float* bg = (const float*)d_in[20];
    const float* bbb = (const float*)d_in[21];
    const float* bm = (const float*)d_in[22];
    const float* bv = (const float*)d_in[23];
    const float* outW = (const float*)d_in[24];
    const float* outb = (const float*)d_in[25];
    float* out = (float*)d_out;

    char* basep = (char*)d_ws;
    size_t off = 0;
    auto alloc = [&](size_t bytes) -> char* {
        char* p = basep + off;
        off = (off + bytes + 255) & ~(size_t)255;
        return p;
    };
    unsigned short* xh = (unsigned short*)alloc((size_t)N * KXH * 2);
    float* x = (float*)alloc((size_t)N * 128 * 4);
    unsigned short* xs = (unsigned short*)alloc((size_t)N * 512 * 2);
    float* a_src = (float*)alloc((size_t)N * 4 * 4);
    float* a_dst = (float*)alloc((size_t)N * 4 * 4);
    int* cnt = (int*)alloc((size_t)N * 4);
    int* rowptr = (int*)alloc((size_t)(N + 1) * 4);
    int* cursor = (int*)alloc((size_t)N * 4);
    int* csrc = (int*)alloc((size_t)(E + N) * 4);
    unsigned short* gatWt = (unsigned short*)alloc((size_t)NLAYERS * 512 * 2176 * 2);
    unsigned short* W1t = (unsigned short*)alloc((size_t)128 * KPAD * 2);
    unsigned short* W2bf = (unsigned short*)alloc((size_t)128 * CTXD * 2);
    unsigned short* cpre = (unsigned short*)alloc((size_t)NG * CTXD * 2);
    unsigned short* Bc = (unsigned short*)alloc((size_t)NLAYERS * 512 * KXH * 2);
    float* cW = (float*)alloc((size_t)NLAYERS * NG * 512 * 4);
    (void)ws_size; (void)n_in; (void)out_size;

    // ---- merged input-only prep ----
    {
        int nbW1t = (128 * KPAD + 255) / 256;
        int nbW2 = (128 * CTXD + 255) / 256;
        int nbCp = (NG * CTXD + 255) / 256;
        int nbCi = (N + 255) / 256;
        int nbEm = (N * 128 + 255) / 256;
        int nbTr = 16 * 68 * 3;
        int e0 = nbW1t, e1 = e0 + nbW2, e2 = e1 + nbCp, e3 = e2 + nbCi, e4 = e3 + nbEm;
        int total = e4 + nbTr;
        k_misc<<<total, 256, 0, stream>>>(W1, W1t, W2, W2bf, ctx, b2, cpre, cnt,
                                          at, embW, embB, x, xh, gatW, gatWt,
                                          N, NG, e0, e1, e2, e3, e4);
    }
    k_cnt<<<(E + 255) / 256, 256, 0, stream>>>(ei, E, cnt);
    // ---- merged RBF + weight-prep GEMMs + Bc copy ----
    {
        int nbRbf = (N + 127) / 128;
        int nbBc = (NLAYERS * 512 * 128 + 255) / 256;
        k_rbfprep<<<nbRbf + 24 + nbBc, 256, 0, stream>>>(pos, W1t, b1, rg, rb, rm, rv, xh,
                                                         gatWt, W2bf, cpre, Bc, cW, N, NG, nbRbf);
    }
    k_scan<<<1, 1024, 0, stream>>>(cnt, rowptr, cursor, N);
    k_fill<<<(E + N + 255) / 256, 256, 0, stream>>>(ei, E, N, cursor, csrc);
    // ---- GAT layers ----
    {
        int nwg = 4 * ((N + 127) / 128);
        for (int l = 0; l < NLAYERS; l++) {
            k_gemm3<<<nwg, 256, 0, stream>>>(xh, N, Bc + (size_t)l * 512 * KXH,
                                             xs, batch, cW + (size_t)l * NG * 512,
                                             atts + l * 512, attd + l * 512, a_src, a_dst);
            k_agg<<<(N + 3) / 4, 256, 0, stream>>>(rowptr, csrc, a_src, a_dst, xs,
                                                   gbias + l * 128, bg + l * 128, bbb + l * 128,
                                                   bm + l * 128, bv + l * 128, x, xh, N);
        }
    }
    k_pool<<<NG, 256, 0, stream>>>(x, batch, outW, outb, out, N);
}